// Round 5
// baseline (7217.303 us; speedup 1.0000x reference)
//
#include <hip/hip_runtime.h>
#include <hip/hip_bf16.h>

// Problem constants (from reference)
#define N_NODES  100000
#define N_EDGES  400000
#define N_GRAPHS 4000
#define IN_DIM   128
#define HID      512
#define N_DESC   200
#define N_CLASSES 2
#define MLP1_OUT 500
#define MLP2_OUT 100
#define XIN_DIM  (HID + N_DESC)   // 712

typedef __hip_bfloat16  bf16;
typedef __hip_bfloat162 bf16x2;

// ---------------------------------------------------------------------------
// Dtype-generic load helpers (FT = float or bf16), all produce fp32.
// ---------------------------------------------------------------------------
__device__ __forceinline__ float ldf(const float* p, size_t i) { return p[i]; }
__device__ __forceinline__ float ldf(const bf16* p, size_t i)  { return __bfloat162float(p[i]); }

__device__ __forceinline__ float2 ld2(const float* p, int i) { return ((const float2*)p)[i]; }
__device__ __forceinline__ float2 ld2(const bf16* p, int i)  {
    return __bfloat1622float2(((const bf16x2*)p)[i]);
}

__device__ __forceinline__ void ld8(const float* p, int i, float* o) {
    float4 a = ((const float4*)p)[2 * i];
    float4 b = ((const float4*)p)[2 * i + 1];
    o[0] = a.x; o[1] = a.y; o[2] = a.z; o[3] = a.w;
    o[4] = b.x; o[5] = b.y; o[6] = b.z; o[7] = b.w;
}
__device__ __forceinline__ void ld8(const bf16* p, int i, float* o) {
    float4 r = ((const float4*)p)[i];          // 8 bf16
    const bf16x2* q = (const bf16x2*)&r;
#pragma unroll
    for (int k = 0; k < 4; k++) {
        float2 f = __bfloat1622float2(q[k]);
        o[2 * k] = f.x; o[2 * k + 1] = f.y;
    }
}

__device__ __forceinline__ void store_out(float* p, float v) { *p = v; }
__device__ __forceinline__ void store_out(bf16* p, float v)  { *p = __float2bfloat16(v); }

// ---------------------------------------------------------------------------
// Runtime dtype detection. Decode each sampled word's LOW 16 bits as bf16:
//   bf16 data  -> low half is a real N(0,1) bf16 value  -> ~100% sane
//   fp32 data  -> low half is random mantissa bits      -> ~21% sane
// flag = 1 (bf16) iff >60% sane.
// ---------------------------------------------------------------------------
__global__ __launch_bounds__(256)
void detect_dtype_kernel(const unsigned* __restrict__ words, unsigned nw,
                         int* __restrict__ flag)
{
    __shared__ int s_cnt;
    if (threadIdx.x == 0) s_cnt = 0;
    __syncthreads();
    const int SAMPLES = 2048;
    int sane = 0;
    for (int i = threadIdx.x; i < SAMPLES; i += 256) {
        size_t idx = (size_t)(((unsigned long long)i * 2654435761ull) % nw);
        unsigned w = words[idx];
        float f = __uint_as_float((w & 0xFFFFu) << 16);
        float a = fabsf(f);
        if (f == 0.0f || (a > 1e-8f && a < 1e8f)) sane++;
    }
    atomicAdd(&s_cnt, sane);
    __syncthreads();
    if (threadIdx.x == 0) *flag = (s_cnt * 10 > SAMPLES * 6) ? 1 : 0;
}

// ---------------------------------------------------------------------------
// Head GEMM: C[M,N] = A[M,K](fp32) @ B[K,N](FT) + bias(FT), relu.
// ---------------------------------------------------------------------------
template<int RELU, typename FT, int MODE, typename TOUT>
__global__ __launch_bounds__(256)
void gemm_kernel(const float* __restrict__ A, const FT* __restrict__ B,
                 const FT* __restrict__ bias, TOUT* __restrict__ C,
                 int M, int N, int K, const int* __restrict__ flag)
{
    if (*flag != MODE) return;
    constexpr int BM = 128, BN = 128, BK = 8, TM = 8, TN = 8;
    __shared__ float As[BK][BM];
    __shared__ float Bs[BK][BN];

    const int tid = threadIdx.x;
    const int tr  = tid >> 4;
    const int tc  = tid & 15;
    const int row0 = blockIdx.y * BM;
    const int col0 = blockIdx.x * BN;

    float acc[TM][TN];
#pragma unroll
    for (int i = 0; i < TM; i++)
#pragma unroll
        for (int j = 0; j < TN; j++) acc[i][j] = 0.f;

    for (int k0 = 0; k0 < K; k0 += BK) {
#pragma unroll
        for (int s = 0; s < 4; s++) {
            int l = tid * 4 + s;
            int i = l >> 3, j = l & 7;
            int gr = row0 + i, gc = k0 + j;
            As[j][i] = (gr < M && gc < K) ? A[(size_t)gr * K + gc] : 0.f;
        }
#pragma unroll
        for (int s = 0; s < 4; s++) {
            int l = tid * 4 + s;
            int j = l >> 7, i = l & 127;
            int gr = k0 + j, gc = col0 + i;
            Bs[j][i] = (gr < K && gc < N) ? ldf(B, (size_t)gr * N + gc) : 0.f;
        }
        __syncthreads();
#pragma unroll
        for (int k = 0; k < BK; k++) {
            float a[TM], b[TN];
#pragma unroll
            for (int i = 0; i < TM; i++) a[i] = As[k][tr * TM + i];
#pragma unroll
            for (int j = 0; j < TN; j++) b[j] = Bs[k][tc * TN + j];
#pragma unroll
            for (int i = 0; i < TM; i++)
#pragma unroll
                for (int j = 0; j < TN; j++)
                    acc[i][j] += a[i] * b[j];
        }
        __syncthreads();
    }

#pragma unroll
    for (int i = 0; i < TM; i++) {
        int gr = row0 + tr * TM + i;
        if (gr >= M) continue;
#pragma unroll
        for (int j = 0; j < TN; j++) {
            int gc = col0 + tc * TN + j;
            if (gc >= N) continue;
            float v = acc[i][j] + ldf(bias, gc);
            if (RELU) v = v > 0.f ? v : 0.f;
            store_out(&C[(size_t)gr * N + gc], v);
        }
    }
}

// ---------------------------------------------------------------------------
// GEMM2 + fused mean-pool: t = relu(A[r,:]@W2 + b2); hg[n2g[n0+r],:] += t.
// ---------------------------------------------------------------------------
template<typename FT, int MODE>
__global__ __launch_bounds__(256)
void gemm_pool_kernel(const float* __restrict__ A, const FT* __restrict__ B,
                      const FT* __restrict__ bias, const int* __restrict__ n2g,
                      float* __restrict__ hg, int n0, int M,
                      const int* __restrict__ flag)
{
    if (*flag != MODE) return;
    constexpr int BM = 128, BK = 8, TM = 8, TN = 8;
    __shared__ float As[BK][BM];
    __shared__ float Bs[BK][128];

    const int tid = threadIdx.x;
    const int tr  = tid >> 4;
    const int tc  = tid & 15;
    const int row0 = blockIdx.y * BM;
    const int col0 = blockIdx.x * 128;   // grid.x = 4

    float acc[TM][TN];
#pragma unroll
    for (int i = 0; i < TM; i++)
#pragma unroll
        for (int j = 0; j < TN; j++) acc[i][j] = 0.f;

    for (int k0 = 0; k0 < HID; k0 += BK) {
#pragma unroll
        for (int s = 0; s < 4; s++) {
            int l = tid * 4 + s;
            int i = l >> 3, j = l & 7;
            int gr = row0 + i;
            As[j][i] = (gr < M) ? A[(size_t)gr * HID + k0 + j] : 0.f;
        }
#pragma unroll
        for (int s = 0; s < 4; s++) {
            int l = tid * 4 + s;
            int j = l >> 7, i = l & 127;
            Bs[j][i] = ldf(B, (size_t)(k0 + j) * HID + col0 + i);
        }
        __syncthreads();
#pragma unroll
        for (int k = 0; k < BK; k++) {
            float a[TM], b[TN];
#pragma unroll
            for (int i = 0; i < TM; i++) a[i] = As[k][tr * TM + i];
#pragma unroll
            for (int j = 0; j < TN; j++) b[j] = Bs[k][tc * TN + j];
#pragma unroll
            for (int i = 0; i < TM; i++)
#pragma unroll
                for (int j = 0; j < TN; j++)
                    acc[i][j] += a[i] * b[j];
        }
        __syncthreads();
    }

    const int colbase = col0 + tc * TN;
    float pend[TN];
    int gprev = -1;
#pragma unroll
    for (int i = 0; i < TM; i++) {
        int r = row0 + tr * TM + i;
        if (r >= M) break;
        int g = n2g[n0 + r];
        if (g != gprev) {
            if (gprev >= 0) {
#pragma unroll
                for (int j = 0; j < TN; j++)
                    atomicAdd(&hg[(size_t)gprev * HID + colbase + j], pend[j]);
            }
#pragma unroll
            for (int j = 0; j < TN; j++) pend[j] = 0.f;
            gprev = g;
        }
#pragma unroll
        for (int j = 0; j < TN; j++) {
            float v = acc[i][j] + ldf(bias, colbase + j);
            pend[j] += (v > 0.f ? v : 0.f);
        }
    }
    if (gprev >= 0) {
#pragma unroll
        for (int j = 0; j < TN; j++)
            atomicAdd(&hg[(size_t)gprev * HID + colbase + j], pend[j]);
    }
}

// ---------------------------------------------------------------------------
// Layer-1 chunked scatter: aggc[(d-n0), 0:128] += feat[src[e], 0:128]
// Wave per edge, grid-stride.
// ---------------------------------------------------------------------------
template<typename FT, int MODE>
__global__ __launch_bounds__(256)
void scatter_feat_chunk(const FT* __restrict__ feat, const int* __restrict__ src,
                        const int* __restrict__ dst, float* __restrict__ aggc,
                        int n0, int n1, const int* __restrict__ flag)
{
    if (*flag != MODE) return;
    int wid  = (blockIdx.x * 256 + threadIdx.x) >> 6;
    int lane = threadIdx.x & 63;
    int nw   = (gridDim.x * 256) >> 6;
    for (int e = wid; e < N_EDGES; e += nw) {
        int d = dst[e];                  // wave-uniform
        if (d < n0 || d >= n1) continue;
        int s = src[e];
        float2 f = ld2(feat + (size_t)s * IN_DIM, lane);
        float* o = aggc + (size_t)(d - n0) * IN_DIM + lane * 2;
        atomicAdd(o + 0, f.x);
        atomicAdd(o + 1, f.y);
    }
}

// aggc chunk (fp32, n floats) -> agg1 (bf16 internal buffer)
__global__ __launch_bounds__(256)
void cvt_bf16_kernel(const float* __restrict__ srcf, bf16* __restrict__ dstb, int n)
{
    int i = blockIdx.x * 256 + threadIdx.x;
    if (i < n) dstb[i] = __float2bfloat16(srcf[i]);
}

// ---------------------------------------------------------------------------
// Layer-2 fused recompute+scatter. Wave per edge (dst in [n0,n1)):
//   h1row = relu(agg1[src] @ W1 + b1); aggc[(dst-n0), :] += h1row
// agg1 is always bf16 (our buffer); W1/b1 are FT.
// ---------------------------------------------------------------------------
template<typename FT, int MODE>
__global__ __launch_bounds__(256)
void gcn2_edge_kernel(const bf16* __restrict__ agg1, const FT* __restrict__ W1,
                      const FT* __restrict__ b1, const int* __restrict__ src,
                      const int* __restrict__ dst, float* __restrict__ aggc,
                      int n0, int n1, const int* __restrict__ flag)
{
    if (*flag != MODE) return;
    int wid  = (blockIdx.x * 256 + threadIdx.x) >> 6;
    int lane = threadIdx.x & 63;
    int nw   = (gridDim.x * 256) >> 6;

    float bias[8];
    ld8(b1, lane, bias);

    for (int e = wid; e < N_EDGES; e += nw) {
        int d = dst[e];                  // wave-uniform
        if (d < n0 || d >= n1) continue;
        int s = src[e];
        float2 af = __bfloat1622float2(((const bf16x2*)(agg1 + (size_t)s * IN_DIM))[lane]);
        float acc[8];
#pragma unroll
        for (int j = 0; j < 8; j++) acc[j] = 0.f;

        for (int kk = 0; kk < 64; kk++) {
            float ak0 = __shfl(af.x, kk);      // k = 2*kk
            float ak1 = __shfl(af.y, kk);      // k = 2*kk+1
            float w0[8], w1[8];
            ld8(W1 + (size_t)(2 * kk) * HID, lane, w0);
            ld8(W1 + (size_t)(2 * kk + 1) * HID, lane, w1);
#pragma unroll
            for (int j = 0; j < 8; j++)
                acc[j] += ak0 * w0[j] + ak1 * w1[j];
        }
        float* o = aggc + (size_t)(d - n0) * HID + lane * 8;
#pragma unroll
        for (int j = 0; j < 8; j++) {
            float v = acc[j] + bias[j];
            atomicAdd(o + j, v > 0.f ? v : 0.f);
        }
    }
}

// counts[g] = number of nodes in graph g
__global__ __launch_bounds__(256)
void count_nodes_kernel(const int* __restrict__ n2g, float* __restrict__ counts)
{
    int n = blockIdx.x * 256 + threadIdx.x;
    if (n < N_NODES) atomicAdd(&counts[n2g[n]], 1.0f);
}

// xin[g, c] = c < HID ? hg[g,c]/max(counts[g],1) : desc[g, c-HID]
template<typename FT, int MODE>
__global__ __launch_bounds__(256)
void build_xin_kernel(const float* __restrict__ hg, const float* __restrict__ counts,
                      const FT* __restrict__ desc, float* __restrict__ xin,
                      const int* __restrict__ flag)
{
    if (*flag != MODE) return;
    int idx = blockIdx.x * 256 + threadIdx.x;
    if (idx >= N_GRAPHS * XIN_DIM) return;
    int g = idx / XIN_DIM;
    int c = idx - g * XIN_DIM;
    float v;
    if (c < HID) {
        float cnt = counts[g];
        v = hg[(size_t)g * HID + c] / (cnt > 1.0f ? cnt : 1.0f);
    } else {
        v = ldf(desc, (size_t)g * N_DESC + (c - HID));
    }
    xin[idx] = v;
}

// out[g, c] = x2[g,:] @ cw[:,c] + cb[c]; output dtype = FT
template<typename FT, int MODE>
__global__ __launch_bounds__(256)
void final_layer_kernel(const float* __restrict__ x2, const FT* __restrict__ cw,
                        const FT* __restrict__ cb, FT* __restrict__ out,
                        const int* __restrict__ flag)
{
    if (*flag != MODE) return;
    int i = blockIdx.x * 256 + threadIdx.x;
    if (i >= N_GRAPHS * N_CLASSES) return;
    int r = i >> 1, c = i & 1;
    float acc = ldf(cb, c);
    const float* x = x2 + (size_t)r * MLP2_OUT;
#pragma unroll 4
    for (int k = 0; k < MLP2_OUT; k++)
        acc += x[k] * ldf(cw, k * N_CLASSES + c);
    store_out(&out[i], acc);
}

// ---------------------------------------------------------------------------
static inline size_t align_up(size_t x, size_t a) { return (x + a - 1) & ~(a - 1); }
static inline int imin(int a, int b) { return a < b ? a : b; }

extern "C" void kernel_launch(void* const* d_in, const int* in_sizes, int n_in,
                              void* d_out, int out_size, void* d_ws, size_t ws_size,
                              hipStream_t stream)
{
    const void* features    = d_in[0];
    const void* descriptors = d_in[1];
    const int*  src         = (const int*)d_in[2];
    const int*  dst         = (const int*)d_in[3];
    const int*  node2graph  = (const int*)d_in[4];
    const void* W1          = d_in[5];
    const void* b1          = d_in[6];
    const void* W2          = d_in[7];
    const void* b2          = d_in[8];
    const void* lw1         = d_in[9];
    const void* lb1         = d_in[10];
    const void* lw2         = d_in[11];
    const void* lb2         = d_in[12];
    const void* cw          = d_in[13];
    const void* cb          = d_in[14];
    (void)in_sizes; (void)n_in; (void)out_size;

    // ---- Workspace layout (hard minimum ~37 MB, ws_size-adaptive) ----
    // [agg1 bf16 25.6MB][hg f32 8.19MB][counts 16KB][flag 256B][aggc f32 rest]
    // Head buffers xin/x1/x2 overlay agg1 (dead after layer-2 loop).
    char* ws = (char*)d_ws;
    size_t off = 0;
    bf16* agg1 = (bf16*)(ws + off);
    off = align_up(off + (size_t)N_NODES * IN_DIM * sizeof(bf16), 256);
    float* hg = (float*)(ws + off);
    off = align_up(off + (size_t)N_GRAPHS * HID * sizeof(float), 256);
    float* counts = (float*)(ws + off);
    off = align_up(off + (size_t)N_GRAPHS * sizeof(float), 256);
    int* dflag = (int*)(ws + off);
    off = align_up(off + 256, 256);
    float* aggc = (float*)(ws + off);

    size_t avail = (ws_size > off + (1u << 20)) ? (ws_size - off - (1u << 20)) : 0;
    long long ncl = (long long)(avail / ((size_t)HID * sizeof(float)));
    if (ncl > N_NODES) ncl = N_NODES;
    if (ncl < 1024)    ncl = 1024;          // ~37 MB absolute floor
    const int NC  = (int)ncl;
    const int NC1 = imin(NC * 4, N_NODES);
    const int nch2 = (N_NODES + NC - 1) / NC;
    const int nch1 = (N_NODES + NC1 - 1) / NC1;

    float* xin = (float*)(ws + 0);                         // 11.39 MB
    float* x1  = (float*)(ws + (size_t)12 * 1024 * 1024);  // 8.0 MB
    float* x2  = (float*)(ws + (size_t)21 * 1024 * 1024);  // 1.6 MB (< 25.6 MB)

    // ---- Detect float-tensor dtype on device (flag: 0=fp32, 1=bf16) ----
    detect_dtype_kernel<<<1, 256, 0, stream>>>(
        (const unsigned*)features, (unsigned)(N_NODES * IN_DIM / 2), dflag);

    // ---- Graph-pool setup ----
    hipMemsetAsync(hg, 0, (size_t)N_GRAPHS * HID * sizeof(float), stream);
    hipMemsetAsync(counts, 0, (size_t)N_GRAPHS * sizeof(float), stream);
    count_nodes_kernel<<<(N_NODES + 255) / 256, 256, 0, stream>>>(node2graph, counts);

    // ---- Layer 1 aggregation (chunked): agg1 = bf16(segment_sum(feat[src], dst))
    for (int c = 0; c < nch1; c++) {
        int n0 = c * NC1, n1 = imin(n0 + NC1, N_NODES), mc = n1 - n0;
        hipMemsetAsync(aggc, 0, (size_t)mc * IN_DIM * sizeof(float), stream);
        scatter_feat_chunk<float, 0><<<2048, 256, 0, stream>>>(
            (const float*)features, src, dst, aggc, n0, n1, dflag);
        scatter_feat_chunk<bf16, 1><<<2048, 256, 0, stream>>>(
            (const bf16*)features, src, dst, aggc, n0, n1, dflag);
        int n = mc * IN_DIM;
        cvt_bf16_kernel<<<(n + 255) / 256, 256, 0, stream>>>(
            aggc, agg1 + (size_t)n0 * IN_DIM, n);
    }

    // ---- Layer 2 (chunked over dst): recompute h1 per edge, scatter, GEMM+pool
    for (int c = 0; c < nch2; c++) {
        int n0 = c * NC, n1 = imin(n0 + NC, N_NODES), mc = n1 - n0;
        hipMemsetAsync(aggc, 0, (size_t)mc * HID * sizeof(float), stream);
        gcn2_edge_kernel<float, 0><<<2048, 256, 0, stream>>>(
            agg1, (const float*)W1, (const float*)b1, src, dst, aggc, n0, n1, dflag);
        gcn2_edge_kernel<bf16, 1><<<2048, 256, 0, stream>>>(
            agg1, (const bf16*)W1, (const bf16*)b1, src, dst, aggc, n0, n1, dflag);
        dim3 grid(HID / 128, (mc + 127) / 128);
        gemm_pool_kernel<float, 0><<<grid, 256, 0, stream>>>(
            aggc, (const float*)W2, (const float*)b2, node2graph, hg, n0, mc, dflag);
        gemm_pool_kernel<bf16, 1><<<grid, 256, 0, stream>>>(
            aggc, (const bf16*)W2, (const bf16*)b2, node2graph, hg, n0, mc, dflag);
    }

    // ---- Head ----
    {
        int nthr = (N_GRAPHS * XIN_DIM + 255) / 256;
        build_xin_kernel<float, 0><<<nthr, 256, 0, stream>>>(
            hg, counts, (const float*)descriptors, xin, dflag);
        build_xin_kernel<bf16, 1><<<nthr, 256, 0, stream>>>(
            hg, counts, (const bf16*)descriptors, xin, dflag);
    }
    {
        dim3 grid((MLP1_OUT + 127) / 128, (N_GRAPHS + 127) / 128);
        gemm_kernel<1, float, 0, float><<<grid, 256, 0, stream>>>(
            xin, (const float*)lw1, (const float*)lb1, x1,
            N_GRAPHS, MLP1_OUT, XIN_DIM, dflag);
        gemm_kernel<1, bf16, 1, float><<<grid, 256, 0, stream>>>(
            xin, (const bf16*)lw1, (const bf16*)lb1, x1,
            N_GRAPHS, MLP1_OUT, XIN_DIM, dflag);
    }
    {
        dim3 grid((MLP2_OUT + 127) / 128, (N_GRAPHS + 127) / 128);
        gemm_kernel<1, float, 0, float><<<grid, 256, 0, stream>>>(
            x1, (const float*)lw2, (const float*)lb2, x2,
            N_GRAPHS, MLP2_OUT, MLP1_OUT, dflag);
        gemm_kernel<1, bf16, 1, float><<<grid, 256, 0, stream>>>(
            x1, (const bf16*)lw2, (const bf16*)lb2, x2,
            N_GRAPHS, MLP2_OUT, MLP1_OUT, dflag);
    }
    {
        int nthr = (N_GRAPHS * N_CLASSES + 255) / 256;
        final_layer_kernel<float, 0><<<nthr, 256, 0, stream>>>(
            x2, (const float*)cw, (const float*)cb, (float*)d_out, dflag);
        final_layer_kernel<bf16, 1><<<nthr, 256, 0, stream>>>(
            x2, (const bf16*)cw, (const bf16*)cb, (bf16*)d_out, dflag);
    }
}